// Round 10
// baseline (6779.280 us; speedup 1.0000x reference)
//
#include <hip/hip_runtime.h>

typedef __attribute__((ext_vector_type(4))) float  f32x4;
typedef __attribute__((ext_vector_type(8))) short  bf16x8;

#define NTHR 512
#define BT   64
#define L2E  1.4426950408889634f

// ---------------- LDS byte map (total 76688 <= 81920 -> 2 blocks/CU) ----------------
// planes: [layer] 8192B each: [64 elems][64 units] bf16 (single, RNE), XOR-swizzled
#define PLANE(L)   ((L)*8192)
#define QBUFP(p)   (24576 + ((p)<<14))    // 2 parity-rotating 16KB stage buffers
#define XFB_OFF    57344                  // [64][4] f32 feedback x, 16B stride (1024B)
#define Y1_OFF     58368                  // [64][34] bf16, 68B row (4352B)
#define Y2_OFF     62720                  // [64][18] bf16, 36B row (2304B)
#define W2L_OFF    65024                  // [16][32] bf16 (1024B)
#define BGL_OFF    66048                  // [3][256] f32 bias sums, log2e-scaled (3072B)
#define B1L_OFF    69120                  // [32] f32
#define B2L_OFF    69248                  // [16] f32
#define B3L_OFF    69312                  // [4] f32
#define W3L_OFF    69328                  // [3][16] f32 (192B)
#define W0L_OFF    69520                  // [256][4] f32, 16B stride, log2e-scaled (4096B)
#define OUT_OFF    73616                  // [64][12] f32 out ring, 4 steps (3072B)
#define LDS_TOTAL  76688

// frag-ordered split weights (gate mats log2e-prescaled): 5 mats * 64KB + w1 8KB
__device__ __align__(16) unsigned char g_wsbuf[335872];

__device__ __forceinline__ unsigned short f2bf(float v) {
    unsigned int x = __float_as_uint(v);
    unsigned int r = x + 0x7fffu + ((x >> 16) & 1u);
    return (unsigned short)(r >> 16);
}
__device__ __forceinline__ float bf2f_lo(unsigned int d) { return __uint_as_float(d << 16); }
__device__ __forceinline__ float bf2f_hi(unsigned int d) { return __uint_as_float(d & 0xffff0000u); }

// gates pre-scaled by log2e (2*log2e for g-gate): pure exp2 forms
__device__ __forceinline__ float fsig2(float y) {
    return __builtin_amdgcn_rcpf(1.0f + __builtin_amdgcn_exp2f(-y));
}
__device__ __forceinline__ float ftanh2(float y) {
    return 1.0f - 2.0f * __builtin_amdgcn_rcpf(1.0f + __builtin_amdgcn_exp2f(y));
}
__device__ __forceinline__ float ftanhc(float c) {
    return 1.0f - 2.0f * __builtin_amdgcn_rcpf(1.0f + __builtin_amdgcn_exp2f(c * (2.0f * L2E)));
}

// ---------------- prologue: frag-order + split-B + log2e prescale (unchanged) ----------------
__global__ void prep_weights(const float* __restrict__ whh0, const float* __restrict__ wih1,
                             const float* __restrict__ whh1, const float* __restrict__ wih2,
                             const float* __restrict__ whh2, const float* __restrict__ w1g)
{
    int gi = blockIdx.x * 256 + threadIdx.x;
    if (gi < 20480) {
        int m = gi >> 12;
        int rem = gi & 4095;
        int b = rem >> 6, l = rem & 63;
        int s = b & 1, ks = (b >> 1) & 1, g = (b >> 2) & 3, ug = b >> 4;
        int row = g * 64 + ug * 16 + (l & 15);
        int kb  = ks * 32 + (l >> 4) * 8;
        float fac = (g == 2) ? (2.0f * L2E) : L2E;
        const float* src = (m == 0) ? whh0 : (m == 1) ? wih1 : (m == 2) ? whh1
                         : (m == 3) ? wih2 : whh2;
        unsigned short o[8];
        #pragma unroll
        for (int i = 0; i < 8; ++i) {
            float v = src[row * 64 + kb + i] * fac;
            unsigned short hh = f2bf(v);
            if (s) {
                float r2 = v - __uint_as_float((unsigned int)hh << 16);
                hh = f2bf(r2);
            }
            o[i] = hh;
        }
        unsigned char* dst = g_wsbuf + m * 65536 + b * 1024 + l * 16;
        #pragma unroll
        for (int i = 0; i < 8; ++i) ((unsigned short*)dst)[i] = o[i];
    } else if (gi < 20992) {
        int g2 = gi - 20480;
        int b = g2 >> 6, l = g2 & 63;
        int s = b & 1, ks = (b >> 1) & 1, nt = b >> 2;
        int row = nt * 16 + (l & 15);
        int kb  = ks * 32 + (l >> 4) * 8;
        unsigned short o[8];
        #pragma unroll
        for (int i = 0; i < 8; ++i) {
            float v = w1g[row * 64 + kb + i];           // w1: unscaled
            unsigned short hh = f2bf(v);
            if (s) {
                float r2 = v - __uint_as_float((unsigned int)hh << 16);
                hh = f2bf(r2);
            }
            o[i] = hh;
        }
        unsigned char* dst = g_wsbuf + 327680 + b * 1024 + l * 16;
        #pragma unroll
        for (int i = 0; i < 8; ++i) ((unsigned short*)dst)[i] = o[i];
    }
}

#define MFMA_(A,B,C) __builtin_amdgcn_mfma_f32_16x16x32_bf16(A, B, C, 0, 0, 0)

// phase barrier: LDS drain -> barrier -> pin (R8-proven form)
#define BARX do { \
    asm volatile("s_waitcnt lgkmcnt(0)" ::: "memory"); \
    __builtin_amdgcn_s_barrier(); \
    __builtin_amdgcn_sched_barrier(0); \
    } while (0)

// 512-thread staging: two dwordx4 chunks per thread per 16KB quarter.
#define LOADQ2(m, ks, s, R0, R1) do { \
    R0 = *(const bf16x8*)(g_wsbuf + (m) * 65536 + \
        ((((tid >> 6) * 2 + 0) * 4 + (ks) * 2 + (s))) * 1024 + (tid & 63) * 16); \
    R1 = *(const bf16x8*)(g_wsbuf + (m) * 65536 + \
        ((((tid >> 6) * 2 + 1) * 4 + (ks) * 2 + (s))) * 1024 + (tid & 63) * 16); \
    } while (0)
#define COMMITQ2(R0, R1, p) do { \
    *(bf16x8*)(lds + QBUFP(p) + ((tid >> 6) * 2 + 0) * 1024 + (tid & 63) * 16) = R0; \
    *(bf16x8*)(lds + QBUFP(p) + ((tid >> 6) * 2 + 1) * 1024 + (tid & 63) * 16) = R1; \
    } while (0)
#define LOADW1(R0) \
    R0 = *(const bf16x8*)(g_wsbuf + 327680 + (tid >> 6) * 1024 + (tid & 63) * 16)
#define COMMITW1(R0, p) \
    *(bf16x8*)(lds + QBUFP(p) + (tid >> 6) * 1024 + (tid & 63) * 16) = R0

#define ACC_INIT(L) do { \
    _Pragma("unroll") for (int g_ = 0; g_ < 4; ++g_) { \
        float b_ = *(const float*)(lds + BGL_OFF + ((L) * 256 + g_ * 64 + u) * 4); \
        f32x4 t_ = {b_, b_, b_, b_}; \
        _Pragma("unroll") for (int mt_ = 0; mt_ < 2; ++mt_) acc[g_][mt_] = t_; \
    } } while (0)

// uniform gate pass: acc += bf16(h) x staged-quarter (hi or lo half of B)
#define GATEP(APL, ks, P) do { \
    bf16x8 b_[4]; \
    _Pragma("unroll") for (int g_ = 0; g_ < 4; ++g_) \
        b_[g_] = *(const bf16x8*)(lds + QBUFP(P) + (ug * 4 + g_) * 1024 + lane * 16); \
    _Pragma("unroll") for (int mt_ = 0; mt_ < 2; ++mt_) { \
        int ab_ = (((mbase + mt_ * 16 + l15) * 128 + (ks) * 64 + l4 * 16)) ^ rswz; \
        bf16x8 ah_ = *(const bf16x8*)(lds + PLANE(APL) + ab_); \
        _Pragma("unroll") for (int g_ = 0; g_ < 4; ++g_) \
            acc[g_][mt_] = MFMA_(ah_, b_[g_], acc[g_][mt_]); \
    } } while (0)

#define CELLW(L, CARR) do { \
    _Pragma("unroll") for (int mt_ = 0; mt_ < 2; ++mt_) \
    _Pragma("unroll") for (int r_ = 0; r_ < 4; ++r_) { \
        float gi_ = fsig2(acc[0][mt_][r_]); \
        float gf_ = fsig2(acc[1][mt_][r_]); \
        float gg_ = ftanh2(acc[2][mt_][r_]); \
        float go_ = fsig2(acc[3][mt_][r_]); \
        float cn_ = gf_ * CARR[mt_ * 4 + r_] + gi_ * gg_; \
        CARR[mt_ * 4 + r_] = cn_; \
        float hn_ = go_ * ftanhc(cn_); \
        int e_ = mbase + mt_ * 16 + l4 * 4 + r_; \
        int wb_ = ((e_ * 128 + u * 2)) ^ ((e_ & 7) << 4); \
        *(unsigned short*)(lds + PLANE(L) + wb_) = f2bf(hn_); \
    } } while (0)

#define XPART do { \
    _Pragma("unroll") for (int mt_ = 0; mt_ < 2; ++mt_) \
    _Pragma("unroll") for (int r_ = 0; r_ < 4; ++r_) { \
        int e_ = mbase + mt_ * 16 + l4 * 4 + r_; \
        f32x4 xv_ = *(const f32x4*)(lds + XFB_OFF + e_ * 16); \
        _Pragma("unroll") for (int g_ = 0; g_ < 4; ++g_) { \
            f32x4 w0_ = *(const f32x4*)(lds + W0L_OFF + (g_ * 64 + u) * 16); \
            acc[g_][mt_][r_] += xv_.x * w0_.x + xv_.y * w0_.y + xv_.z * w0_.z; \
        } } } while (0)

#define MLP1(P) do { \
    int Mt_ = wv >> 1, half_ = wv & 1; \
    float b1_ = *(const float*)(lds + B1L_OFF + (half_ * 16 + l15) * 4); \
    f32x4 a1_ = {b1_, b1_, b1_, b1_}; \
    _Pragma("unroll") for (int ks_ = 0; ks_ < 2; ++ks_) { \
        int ab_ = (((Mt_ * 16 + l15) * 128 + ks_ * 64 + l4 * 16)) ^ rswz; \
        bf16x8 ah_ = *(const bf16x8*)(lds + PLANE(2) + ab_); \
        bf16x8 wh_ = *(const bf16x8*)(lds + QBUFP(P) + ((half_ * 2 + ks_) * 2 + 0) * 1024 + lane * 16); \
        bf16x8 wl_ = *(const bf16x8*)(lds + QBUFP(P) + ((half_ * 2 + ks_) * 2 + 1) * 1024 + lane * 16); \
        a1_ = MFMA_(ah_, wh_, a1_); \
        a1_ = MFMA_(ah_, wl_, a1_); \
    } \
    _Pragma("unroll") for (int r_ = 0; r_ < 4; ++r_) { \
        float y_ = a1_[r_]; y_ = (y_ >= 0.f) ? y_ : 0.01f * y_; \
        int e_ = Mt_ * 16 + l4 * 4 + r_; \
        *(unsigned short*)(lds + Y1_OFF + e_ * 68 + half_ * 32 + l15 * 2) = f2bf(y_); \
    } } while (0)

#define MLP2 do { \
    int e2_ = tid & 63, rg_ = tid >> 6; \
    float a2_[2]; \
    _Pragma("unroll") for (int m_ = 0; m_ < 2; ++m_) \
        a2_[m_] = *(const float*)(lds + B2L_OFF + (rg_ * 2 + m_) * 4); \
    _Pragma("unroll") for (int kd_ = 0; kd_ < 16; ++kd_) { \
        unsigned int d_ = *(const unsigned int*)(lds + Y1_OFF + e2_ * 68 + kd_ * 4); \
        float v0_ = bf2f_lo(d_), v1_ = bf2f_hi(d_); \
        _Pragma("unroll") for (int m_ = 0; m_ < 2; ++m_) { \
            unsigned int w_ = *(const unsigned int*)(lds + W2L_OFF + ((rg_ * 2 + m_) * 32 + kd_ * 2) * 2); \
            a2_[m_] = fmaf(v0_, bf2f_lo(w_), a2_[m_]); \
            a2_[m_] = fmaf(v1_, bf2f_hi(w_), a2_[m_]); \
        } } \
    _Pragma("unroll") for (int m_ = 0; m_ < 2; ++m_) { \
        float y_ = a2_[m_]; y_ = (y_ >= 0.f) ? y_ : 0.01f * y_; \
        *(unsigned short*)(lds + Y2_OFF + e2_ * 36 + (rg_ * 2 + m_) * 2) = f2bf(y_); \
    } } while (0)

#define MLP3_OUT do { \
    if (tid < 192) { \
        int e3_ = tid & 63, r3_ = tid >> 6; \
        float a3_ = *(const float*)(lds + B3L_OFF + r3_ * 4); \
        _Pragma("unroll") for (int kd_ = 0; kd_ < 8; ++kd_) { \
            unsigned int d_ = *(const unsigned int*)(lds + Y2_OFF + e3_ * 36 + kd_ * 4); \
            a3_ = fmaf(bf2f_lo(d_), *(const float*)(lds + W3L_OFF + (r3_ * 16 + kd_ * 2) * 4),     a3_); \
            a3_ = fmaf(bf2f_hi(d_), *(const float*)(lds + W3L_OFF + (r3_ * 16 + kd_ * 2 + 1) * 4), a3_); \
        } \
        float y_ = (a3_ >= 0.f) ? a3_ : 0.01f * a3_; \
        *(float*)(lds + XFB_OFF + e3_ * 16 + r3_ * 4) = y_; \
        *(float*)(lds + OUT_OFF + e3_ * 48 + (t & 3) * 12 + r3_ * 4) = y_; \
    } } while (0)

// ---------------- main persistent kernel: 512 thr, 2 blocks/CU ----------------
extern "C" __global__ void __launch_bounds__(NTHR)
__attribute__((amdgpu_waves_per_eu(4, 4)))
lstm_mfma(const float* __restrict__ noise,
          const float* __restrict__ wih0, const float* __restrict__ whh0,
          const float* __restrict__ bih0, const float* __restrict__ bhh0,
          const float* __restrict__ wih1, const float* __restrict__ whh1,
          const float* __restrict__ bih1, const float* __restrict__ bhh1,
          const float* __restrict__ wih2, const float* __restrict__ whh2,
          const float* __restrict__ bih2, const float* __restrict__ bhh2,
          const float* __restrict__ w1g, const float* __restrict__ b1g,
          const float* __restrict__ w2g, const float* __restrict__ b2g,
          const float* __restrict__ w3g, const float* __restrict__ b3g,
          const int* __restrict__ lenp, float* __restrict__ out)
{
    extern __shared__ unsigned char lds[];
    const int tid  = threadIdx.x;
    const int lane = tid & 63;
    const int wv   = tid >> 6;       // wave 0..7
    const int ug   = wv & 3;         // unit group (16 units)
    const int mh   = wv >> 2;        // M half 0..1
    const int l15  = lane & 15;
    const int l4   = lane >> 4;      // k-group
    const int u    = ug * 16 + l15;  // unit 0..63
    const int mbase = mh * 32;
    const int rswz  = (lane & 7) << 4;
    const int T = *lenp;
    const long eg0  = (long)blockIdx.x * BT;
    const long outs = 3L * T;

    // per-thread recurrent c state: 8 (unit,elem) pairs per layer
    float c0[8], c1[8], c2[8];
    #pragma unroll
    for (int i = 0; i < 8; ++i) { c0[i] = 0.f; c1[i] = 0.f; c2[i] = 0.f; }

    // staging registers (3-deep rotation, 2 chunks each)
    bf16x8 RA0, RA1, RB0, RB1, RC0, RC1;

    // warmup loads (q0,q1,q2)
    LOADQ2(0, 0, 0, RA0, RA1);
    LOADQ2(0, 1, 0, RB0, RB1);
    LOADQ2(0, 0, 1, RC0, RC1);

    // ---- LDS init ----
    for (int i = tid; i < 24576 / 4; i += NTHR) ((unsigned int*)lds)[i] = 0u;  // h planes = 0
    if (tid < BT) {
        const float* np = noise + (eg0 + tid) * 3;
        f32x4 xv = {np[0], np[1], np[2], 0.f};
        *(f32x4*)(lds + XFB_OFF + tid * 16) = xv;
    }
    *(unsigned short*)(lds + W2L_OFF + tid * 2) = f2bf(w2g[tid]);   // tid<512 == NTHR
    for (int i = tid; i < 768; i += NTHR) {                          // bias sums, log2e-scaled
        int l = i >> 8, r = i & 255, g = r >> 6;
        float fac = (g == 2) ? (2.0f * L2E) : L2E;
        const float* bi = (l == 0) ? bih0 : ((l == 1) ? bih1 : bih2);
        const float* bh = (l == 0) ? bhh0 : ((l == 1) ? bhh1 : bhh2);
        *(float*)(lds + BGL_OFF + i * 4) = (bi[r] + bh[r]) * fac;
    }
    if (tid < 256) {                                                 // wih0, log2e-scaled
        int g = tid >> 6;
        float fac = (g == 2) ? (2.0f * L2E) : L2E;
        f32x4 wv0 = {wih0[tid * 3] * fac, wih0[tid * 3 + 1] * fac,
                     wih0[tid * 3 + 2] * fac, 0.f};
        *(f32x4*)(lds + W0L_OFF + tid * 16) = wv0;
    }
    if (tid < 32) *(float*)(lds + B1L_OFF + tid * 4) = b1g[tid];
    if (tid < 16) *(float*)(lds + B2L_OFF + tid * 4) = b2g[tid];
    if (tid < 3)  *(float*)(lds + B3L_OFF + tid * 4) = b3g[tid];
    if (tid < 48) *(float*)(lds + W3L_OFF + tid * 4) = w3g[tid];

    __syncthreads();                 // init visible (full drain, once)
    COMMITQ2(RA0, RA1, 0);           // q0 -> buf0
    __syncthreads();                 // buf0 ready

    f32x4 acc[4][2];

    #pragma unroll 1
    for (int t = 0; t < T; ++t) {
        const int bp = t & 1;
        // ----- layer 0: whh0 q0..q3 (A = plane0 old) -----
        COMMITQ2(RB0, RB1, bp ^ 1); LOADQ2(0, 1, 1, RA0, RA1);   // commit q1, load q3
        ACC_INIT(0); XPART;
        GATEP(0, 0, bp);                                          // q0 hi-k0
        BARX;
        COMMITQ2(RC0, RC1, bp); LOADQ2(1, 0, 0, RB0, RB1);       // commit q2, load q4
        GATEP(0, 1, bp ^ 1);                                      // q1 hi-k1
        BARX;
        COMMITQ2(RA0, RA1, bp ^ 1); LOADQ2(1, 1, 0, RC0, RC1);   // commit q3, load q5
        GATEP(0, 0, bp);                                          // q2 lo-k0
        BARX;
        COMMITQ2(RB0, RB1, bp); LOADQ2(1, 0, 1, RA0, RA1);       // commit q4, load q6
        GATEP(0, 1, bp ^ 1);                                      // q3 lo-k1
        BARX;
        CELLW(0, c0);                                             // h0 -> plane0
        BARX;
        // ----- layer 1: wih1 q4..q7 (A=plane0 new), whh1 q8..q11 (A=plane1 old) -----
        ACC_INIT(1);
        COMMITQ2(RC0, RC1, bp ^ 1); LOADQ2(1, 1, 1, RB0, RB1);   // commit q5, load q7
        GATEP(0, 0, bp);                                          // q4
        BARX;
        COMMITQ2(RA0, RA1, bp); LOADQ2(2, 0, 0, RC0, RC1);       // commit q6, load q8
        GATEP(0, 1, bp ^ 1);                                      // q5
        BARX;
        COMMITQ2(RB0, RB1, bp ^ 1); LOADQ2(2, 1, 0, RA0, RA1);   // commit q7, load q9
        GATEP(0, 0, bp);                                          // q6
        BARX;
        COMMITQ2(RC0, RC1, bp); LOADQ2(2, 0, 1, RB0, RB1);       // commit q8, load q10
        GATEP(0, 1, bp ^ 1);                                      // q7
        BARX;
        COMMITQ2(RA0, RA1, bp ^ 1); LOADQ2(2, 1, 1, RC0, RC1);   // commit q9, load q11
        GATEP(1, 0, bp);                                          // q8
        BARX;
        COMMITQ2(RB0, RB1, bp); LOADQ2(3, 0, 0, RA0, RA1);       // commit q10, load q12
        GATEP(1, 1, bp ^ 1);                                      // q9
        BARX;
        COMMITQ2(RC0, RC1, bp ^ 1); LOADQ2(3, 1, 0, RB0, RB1);   // commit q11, load q13
        GATEP(1, 0, bp);                                          // q10
        BARX;
        COMMITQ2(RA0, RA1, bp); LOADQ2(3, 0, 1, RC0, RC1);       // commit q12, load q14
        GATEP(1, 1, bp ^ 1);                                      // q11
        BARX;
        CELLW(1, c1);                                             // h1 -> plane1
        BARX;
        // ----- layer 2: wih2 q12..q15 (A=plane1 new), whh2 q16..q19 (A=plane2 old) -----
        ACC_INIT(2);
        COMMITQ2(RB0, RB1, bp ^ 1); LOADQ2(3, 1, 1, RA0, RA1);   // commit q13, load q15
        GATEP(1, 0, bp);                                          // q12
        BARX;
        COMMITQ2(RC0, RC1, bp); LOADQ2(4, 0, 0, RB0, RB1);       // commit q14, load q16
        GATEP(1, 1, bp ^ 1);                                      // q13
        BARX;
        COMMITQ2(RA0, RA1, bp ^ 1); LOADQ2(4, 1, 0, RC0, RC1);   // commit q15, load q17
        GATEP(1, 0, bp);                                          // q14
        BARX;
        COMMITQ2(RB0, RB1, bp); LOADQ2(4, 0, 1, RA0, RA1);       // commit q16, load q18
        GATEP(1, 1, bp ^ 1);                                      // q15
        BARX;
        COMMITQ2(RC0, RC1, bp ^ 1); LOADQ2(4, 1, 1, RB0, RB1);   // commit q17, load q19
        GATEP(2, 0, bp);                                          // q16
        BARX;
        COMMITQ2(RA0, RA1, bp); LOADW1(RC0);                     // commit q18, load q20 (w1)
        GATEP(2, 1, bp ^ 1);                                      // q17
        BARX;
        COMMITQ2(RB0, RB1, bp ^ 1); LOADQ2(0, 0, 0, RA0, RA1);   // commit q19, load q0'
        GATEP(2, 0, bp);                                          // q18
        BARX;
        COMMITW1(RC0, bp); LOADQ2(0, 1, 0, RB0, RB1);            // commit q20(w1), load q1'
        GATEP(2, 1, bp ^ 1);                                      // q19
        BARX;
        CELLW(2, c2);                                             // h2 -> plane2
        BARX;
        // ----- MLP head -----
        COMMITQ2(RA0, RA1, bp ^ 1); LOADQ2(0, 0, 1, RC0, RC1);   // commit q0', load q2'
        MLP1(bp);                                                 // y1 via MFMA (A=plane2, B=w1)
        BARX;
        MLP2;                                                     // y1 -> y2 (VALU)
        BARX;
        MLP3_OUT;                                                 // y2 -> XFB + out ring
        if ((t & 3) == 3) {                                       // flush 4 buffered steps
            BARX;
            long tb = t - 3;
            #pragma unroll
            for (int it = 0; it < 2; ++it) {
                int i = it * NTHR + tid;
                if (i < 768) {
                    int e = i / 12, j = i - e * 12;
                    out[(eg0 + e) * outs + tb * 3 + j] =
                        *(const float*)(lds + OUT_OFF + e * 48 + j * 4);
                }
            }
        }
        BARX;                                                     // step boundary
    }

    // tail flush (T not multiple of 4)
    int nst = T & 3;
    if (nst) {
        int nfl = BT * nst * 3;
        for (int i = tid; i < nfl; i += NTHR) {
            int e = i / (nst * 3), j = i - e * (nst * 3);
            out[(eg0 + e) * outs + (long)(T - nst) * 3 + j] =
                *(const float*)(lds + OUT_OFF + e * 48 + j * 4);
        }
    }
}

extern "C" void kernel_launch(void* const* d_in, const int* in_sizes, int n_in,
                              void* d_out, int out_size, void* d_ws, size_t ws_size,
                              hipStream_t stream)
{
    const float* noise = (const float*)d_in[0];
    const float* wih0  = (const float*)d_in[1];
    const float* whh0  = (const float*)d_in[2];
    const float* bih0  = (const float*)d_in[3];
    const float* bhh0  = (const float*)d_in[4];
    const float* wih1  = (const float*)d_in[5];
    const float* whh1  = (const float*)d_in[6];
    const float* bih1  = (const float*)d_in[7];
    const float* bhh1  = (const float*)d_in[8];
    const float* wih2  = (const float*)d_in[9];
    const float* whh2  = (const float*)d_in[10];
    const float* bih2  = (const float*)d_in[11];
    const float* bhh2  = (const float*)d_in[12];
    const float* w1g   = (const float*)d_in[13];
    const float* b1g   = (const float*)d_in[14];
    const float* w2g   = (const float*)d_in[15];
    const float* b2g   = (const float*)d_in[16];
    const float* w3g   = (const float*)d_in[17];
    const float* b3g   = (const float*)d_in[18];
    const int*   lenp  = (const int*)d_in[19];
    float* out = (float*)d_out;

    int B = in_sizes[0] / 3;              // 32768
    int grid = B / BT;                    // 512 blocks = 2 per CU

    prep_weights<<<82, 256, 0, stream>>>(whh0, wih1, whh1, wih2, whh2, w1g);

    hipFuncSetAttribute((const void*)lstm_mfma,
                        hipFuncAttributeMaxDynamicSharedMemorySize, LDS_TOTAL);
    lstm_mfma<<<grid, NTHR, LDS_TOTAL, stream>>>(
        noise, wih0, whh0, bih0, bhh0, wih1, whh1, bih1, bhh1,
        wih2, whh2, bih2, bhh2, w1g, b1g, w2g, b2g, w3g, b3g, lenp, out);
}

// Round 11
// 3956.725 us; speedup vs baseline: 1.7134x; 1.7134x over previous
//
#include <hip/hip_runtime.h>

typedef __attribute__((ext_vector_type(4))) float  f32x4;
typedef __attribute__((ext_vector_type(8))) short  bf16x8;

#define NTHR 1024
#define BT   128
#define L2E  1.4426950408889634f

// ---------------- LDS byte map (total 112016 <= 163840) ----------------
// planes: [layer] 16384B each: [128 elems][64 units] bf16 (single, RNE), XOR-swizzled
#define PLANE(L)   ((L)*16384)
#define QBUFP(p)   (49152 + ((p)<<14))    // 2 parity-rotating 16KB stage buffers
#define XFB_OFF    81920                  // [128][4] f32 feedback x, 16B stride (2048B)
#define Y1_OFF     83968                  // [128][34] bf16, 68B row (8704B)
#define Y2_OFF     92672                  // [128][18] bf16, 36B row (4608B)
#define W2L_OFF    97280                  // [16][32] bf16 (1024B)
#define BGL_OFF    98304                  // [3][256] f32 bias sums, log2e-scaled (3072B)
#define B1L_OFF    101376                 // [32] f32
#define B2L_OFF    101504                 // [16] f32
#define B3L_OFF    101568                 // [4] f32
#define W3L_OFF    101584                 // [3][16] f32 (192B)
#define W0L_OFF    101776                 // [256][4] f32, 16B stride, log2e-scaled (4096B)
#define OUT_OFF    105872                 // [128][12] f32 out ring, 4 steps (6144B)
#define LDS_TOTAL  112016

// frag-ordered SINGLE-bf16 weights (gate mats log2e-prescaled): 5 mats * 32KB + w1 4KB
__device__ __align__(16) unsigned char g_wsbuf[167936];

__device__ __forceinline__ unsigned short f2bf(float v) {
    unsigned int x = __float_as_uint(v);
    unsigned int r = x + 0x7fffu + ((x >> 16) & 1u);
    return (unsigned short)(r >> 16);
}
__device__ __forceinline__ float bf2f_lo(unsigned int d) { return __uint_as_float(d << 16); }
__device__ __forceinline__ float bf2f_hi(unsigned int d) { return __uint_as_float(d & 0xffff0000u); }

// gates pre-scaled by log2e (2*log2e for g-gate): pure exp2 forms
__device__ __forceinline__ float fsig2(float y) {
    return __builtin_amdgcn_rcpf(1.0f + __builtin_amdgcn_exp2f(-y));
}
__device__ __forceinline__ float ftanh2(float y) {
    return 1.0f - 2.0f * __builtin_amdgcn_rcpf(1.0f + __builtin_amdgcn_exp2f(y));
}
__device__ __forceinline__ float ftanhc(float c) {
    return 1.0f - 2.0f * __builtin_amdgcn_rcpf(1.0f + __builtin_amdgcn_exp2f(c * (2.0f * L2E)));
}

// ---------------- prologue: frag-order single-bf16 + log2e prescale ----------------
// gate mats: 32 blocks/mat of 1KB: b = (ug*4+g)*2 + ks; lane l covers row g*64+ug*16+(l&15),
// k = ks*32 + (l>>4)*8 .. +8.  w1: 4 blocks: b = hf*2 + ks.
__global__ void prep_weights(const float* __restrict__ whh0, const float* __restrict__ wih1,
                             const float* __restrict__ whh1, const float* __restrict__ wih2,
                             const float* __restrict__ whh2, const float* __restrict__ w1g)
{
    int gi = blockIdx.x * 256 + threadIdx.x;
    if (gi < 10240) {
        int m = gi / 2048;
        int rem = gi & 2047;
        int b = rem >> 6, l = rem & 63;
        int ks = b & 1, g = (b >> 1) & 3, ug = b >> 3;
        int row = g * 64 + ug * 16 + (l & 15);
        int kb  = ks * 32 + (l >> 4) * 8;
        float fac = (g == 2) ? (2.0f * L2E) : L2E;
        const float* src = (m == 0) ? whh0 : (m == 1) ? wih1 : (m == 2) ? whh1
                         : (m == 3) ? wih2 : whh2;
        unsigned short o[8];
        #pragma unroll
        for (int i = 0; i < 8; ++i)
            o[i] = f2bf(src[row * 64 + kb + i] * fac);
        unsigned char* dst = g_wsbuf + m * 32768 + b * 1024 + l * 16;
        #pragma unroll
        for (int i = 0; i < 8; ++i) ((unsigned short*)dst)[i] = o[i];
    } else if (gi < 10496) {
        int g2 = gi - 10240;
        int b = g2 >> 6, l = g2 & 63;
        int ks = b & 1, hf = b >> 1;
        int row = hf * 16 + (l & 15);
        int kb  = ks * 32 + (l >> 4) * 8;
        unsigned short o[8];
        #pragma unroll
        for (int i = 0; i < 8; ++i)
            o[i] = f2bf(w1g[row * 64 + kb + i]);        // w1: unscaled
        unsigned char* dst = g_wsbuf + 163840 + b * 1024 + l * 16;
        #pragma unroll
        for (int i = 0; i < 8; ++i) ((unsigned short*)dst)[i] = o[i];
    }
}

#define MFMA_(A,B,C) __builtin_amdgcn_mfma_f32_16x16x32_bf16(A, B, C, 0, 0, 0)

// phase barrier (R8-proven): LDS drain -> barrier -> sched pin.
// Global loads stay in flight (counted vmcnt at the ds_write use site).
#define BARX do { \
    asm volatile("s_waitcnt lgkmcnt(0)" ::: "memory"); \
    __builtin_amdgcn_s_barrier(); \
    __builtin_amdgcn_sched_barrier(0); \
    } while (0)

// 1024-thread staging: one dwordx4 per thread per 16KB quarter (m, ks).
#define LOADQ(m, ks, R) \
    R = *(const bf16x8*)(g_wsbuf + (m) * 32768 + \
        ((tid >> 6) * 2 + (ks)) * 1024 + (tid & 63) * 16)
#define COMMITQ(R, p) \
    *(bf16x8*)(lds + QBUFP(p) + tid * 16) = R
#define LOADW1(R) do { if (tid < 256) \
    R = *(const bf16x8*)(g_wsbuf + 163840 + (tid >> 6) * 1024 + (tid & 63) * 16); } while (0)
#define COMMITW1(R, p) do { if (tid < 256) \
    *(bf16x8*)(lds + QBUFP(p) + tid * 16) = R; } while (0)

#define ACC_INIT(L) do { \
    _Pragma("unroll") for (int g_ = 0; g_ < 4; ++g_) { \
        float b_ = *(const float*)(lds + BGL_OFF + ((L) * 256 + g_ * 64 + u) * 4); \
        f32x4 t_ = {b_, b_, b_, b_}; \
        _Pragma("unroll") for (int mt_ = 0; mt_ < 2; ++mt_) acc[g_][mt_] = t_; \
    } } while (0)

// single-pass gate: acc += bf16(h) x staged quarter (16 MFMA, 6 ds_read_b128)
#define GATEP(APL, ks, P) do { \
    bf16x8 b_[4]; \
    _Pragma("unroll") for (int g_ = 0; g_ < 4; ++g_) \
        b_[g_] = *(const bf16x8*)(lds + QBUFP(P) + (ug * 4 + g_) * 1024 + lane * 16); \
    _Pragma("unroll") for (int mt_ = 0; mt_ < 2; ++mt_) { \
        int ab_ = (((mbase + mt_ * 16 + l15) * 128 + (ks) * 64 + l4 * 16)) ^ rswz; \
        bf16x8 ah_ = *(const bf16x8*)(lds + PLANE(APL) + ab_); \
        _Pragma("unroll") for (int g_ = 0; g_ < 4; ++g_) \
            acc[g_][mt_] = MFMA_(ah_, b_[g_], acc[g_][mt_]); \
    } } while (0)

#define CELLW(L, CARR) do { \
    _Pragma("unroll") for (int mt_ = 0; mt_ < 2; ++mt_) \
    _Pragma("unroll") for (int r_ = 0; r_ < 4; ++r_) { \
        float gi_ = fsig2(acc[0][mt_][r_]); \
        float gf_ = fsig2(acc[1][mt_][r_]); \
        float gg_ = ftanh2(acc[2][mt_][r_]); \
        float go_ = fsig2(acc[3][mt_][r_]); \
        float cn_ = gf_ * CARR[mt_ * 4 + r_] + gi_ * gg_; \
        CARR[mt_ * 4 + r_] = cn_; \
        float hn_ = go_ * ftanhc(cn_); \
        int e_ = mbase + mt_ * 16 + l4 * 4 + r_; \
        int wb_ = ((e_ * 128 + u * 2)) ^ ((e_ & 7) << 4); \
        *(unsigned short*)(lds + PLANE(L) + wb_) = f2bf(hn_); \
    } } while (0)

#define XPART do { \
    _Pragma("unroll") for (int mt_ = 0; mt_ < 2; ++mt_) \
    _Pragma("unroll") for (int r_ = 0; r_ < 4; ++r_) { \
        int e_ = mbase + mt_ * 16 + l4 * 4 + r_; \
        f32x4 xv_ = *(const f32x4*)(lds + XFB_OFF + e_ * 16); \
        _Pragma("unroll") for (int g_ = 0; g_ < 4; ++g_) { \
            f32x4 w0_ = *(const f32x4*)(lds + W0L_OFF + (g_ * 64 + u) * 16); \
            acc[g_][mt_][r_] += xv_.x * w0_.x + xv_.y * w0_.y + xv_.z * w0_.z; \
        } } } while (0)

#define MLP1(P) do { \
    int Mt_ = wv >> 1, half_ = wv & 1; \
    float b1_ = *(const float*)(lds + B1L_OFF + (half_ * 16 + l15) * 4); \
    f32x4 a1_ = {b1_, b1_, b1_, b1_}; \
    _Pragma("unroll") for (int ks_ = 0; ks_ < 2; ++ks_) { \
        int ab_ = (((Mt_ * 16 + l15) * 128 + ks_ * 64 + l4 * 16)) ^ rswz; \
        bf16x8 ah_ = *(const bf16x8*)(lds + PLANE(2) + ab_); \
        bf16x8 wh_ = *(const bf16x8*)(lds + QBUFP(P) + (half_ * 2 + ks_) * 1024 + lane * 16); \
        a1_ = MFMA_(ah_, wh_, a1_); \
    } \
    _Pragma("unroll") for (int r_ = 0; r_ < 4; ++r_) { \
        float y_ = a1_[r_]; y_ = (y_ >= 0.f) ? y_ : 0.01f * y_; \
        int e_ = Mt_ * 16 + l4 * 4 + r_; \
        *(unsigned short*)(lds + Y1_OFF + e_ * 68 + half_ * 32 + l15 * 2) = f2bf(y_); \
    } } while (0)

#define MLP2 do { \
    int e2_ = tid & 127, rg_ = tid >> 7; \
    float a2_[2]; \
    _Pragma("unroll") for (int m_ = 0; m_ < 2; ++m_) \
        a2_[m_] = *(const float*)(lds + B2L_OFF + (rg_ * 2 + m_) * 4); \
    _Pragma("unroll") for (int kd_ = 0; kd_ < 16; ++kd_) { \
        unsigned int d_ = *(const unsigned int*)(lds + Y1_OFF + e2_ * 68 + kd_ * 4); \
        float v0_ = bf2f_lo(d_), v1_ = bf2f_hi(d_); \
        _Pragma("unroll") for (int m_ = 0; m_ < 2; ++m_) { \
            unsigned int w_ = *(const unsigned int*)(lds + W2L_OFF + ((rg_ * 2 + m_) * 32 + kd_ * 2) * 2); \
            a2_[m_] = fmaf(v0_, bf2f_lo(w_), a2_[m_]); \
            a2_[m_] = fmaf(v1_, bf2f_hi(w_), a2_[m_]); \
        } } \
    _Pragma("unroll") for (int m_ = 0; m_ < 2; ++m_) { \
        float y_ = a2_[m_]; y_ = (y_ >= 0.f) ? y_ : 0.01f * y_; \
        *(unsigned short*)(lds + Y2_OFF + e2_ * 36 + (rg_ * 2 + m_) * 2) = f2bf(y_); \
    } } while (0)

#define MLP3_OUT do { \
    if (tid < 384) { \
        int e3_ = tid & 127, r3_ = tid >> 7; \
        float a3_ = *(const float*)(lds + B3L_OFF + r3_ * 4); \
        _Pragma("unroll") for (int kd_ = 0; kd_ < 8; ++kd_) { \
            unsigned int d_ = *(const unsigned int*)(lds + Y2_OFF + e3_ * 36 + kd_ * 4); \
            a3_ = fmaf(bf2f_lo(d_), *(const float*)(lds + W3L_OFF + (r3_ * 16 + kd_ * 2) * 4),     a3_); \
            a3_ = fmaf(bf2f_hi(d_), *(const float*)(lds + W3L_OFF + (r3_ * 16 + kd_ * 2 + 1) * 4), a3_); \
        } \
        float y_ = (a3_ >= 0.f) ? a3_ : 0.01f * a3_; \
        *(float*)(lds + XFB_OFF + e3_ * 16 + r3_ * 4) = y_; \
        *(float*)(lds + OUT_OFF + e3_ * 48 + (t & 3) * 12 + r3_ * 4) = y_; \
    } } while (0)

// ---------------- main persistent kernel ----------------
extern "C" __global__ void __launch_bounds__(NTHR)
__attribute__((amdgpu_waves_per_eu(4, 4)))
lstm_mfma(const float* __restrict__ noise,
          const float* __restrict__ wih0, const float* __restrict__ whh0,
          const float* __restrict__ bih0, const float* __restrict__ bhh0,
          const float* __restrict__ wih1, const float* __restrict__ whh1,
          const float* __restrict__ bih1, const float* __restrict__ bhh1,
          const float* __restrict__ wih2, const float* __restrict__ whh2,
          const float* __restrict__ bih2, const float* __restrict__ bhh2,
          const float* __restrict__ w1g, const float* __restrict__ b1g,
          const float* __restrict__ w2g, const float* __restrict__ b2g,
          const float* __restrict__ w3g, const float* __restrict__ b3g,
          const int* __restrict__ lenp, float* __restrict__ out)
{
    extern __shared__ unsigned char lds[];
    const int tid  = threadIdx.x;
    const int lane = tid & 63;
    const int wv   = tid >> 6;       // wave 0..15
    const int ug   = wv & 3;         // unit group (16 units)
    const int mh   = wv >> 2;        // M quarter 0..3
    const int l15  = lane & 15;
    const int l4   = lane >> 4;      // k-group
    const int u    = ug * 16 + l15;  // unit 0..63
    const int mbase = mh * 32;
    const int rswz  = (lane & 7) << 4;
    const int T = *lenp;
    const long eg0  = (long)blockIdx.x * BT;
    const long outs = 3L * T;

    // per-thread recurrent c state: 8 (unit,elem) pairs per layer
    float c0[8], c1[8], c2[8];
    #pragma unroll
    for (int i = 0; i < 8; ++i) { c0[i] = 0.f; c1[i] = 0.f; c2[i] = 0.f; }

    // staging registers (3-deep rotation; ring shifts by 2 per step -> renamed at step end)
    bf16x8 RA, RB, RC;

    // warmup loads: q0=(0,0), q1=(0,1), q2=(1,0)
    LOADQ(0, 0, RA);
    LOADQ(0, 1, RB);
    LOADQ(1, 0, RC);

    // ---- LDS init ----
    for (int i = tid; i < 49152 / 4; i += NTHR) ((unsigned int*)lds)[i] = 0u;  // h planes = 0
    if (tid < BT) {
        const float* np = noise + (eg0 + tid) * 3;
        f32x4 xv = {np[0], np[1], np[2], 0.f};
        *(f32x4*)(lds + XFB_OFF + tid * 16) = xv;
    }
    if (tid < 512) *(unsigned short*)(lds + W2L_OFF + tid * 2) = f2bf(w2g[tid]);
    if (tid < 768) {                                   // bias sums, log2e-scaled
        int l = tid >> 8, r = tid & 255, g = r >> 6;
        float fac = (g == 2) ? (2.0f * L2E) : L2E;
        const float* bi = (l == 0) ? bih0 : ((l == 1) ? bih1 : bih2);
        const float* bh = (l == 0) ? bhh0 : ((l == 1) ? bhh1 : bhh2);
        *(float*)(lds + BGL_OFF + tid * 4) = (bi[r] + bh[r]) * fac;
    }
    if (tid < 256) {                                   // wih0, log2e-scaled, 16B stride
        int g = tid >> 6;
        float fac = (g == 2) ? (2.0f * L2E) : L2E;
        f32x4 wv0 = {wih0[tid * 3] * fac, wih0[tid * 3 + 1] * fac,
                     wih0[tid * 3 + 2] * fac, 0.f};
        *(f32x4*)(lds + W0L_OFF + tid * 16) = wv0;
    }
    if (tid < 32) *(float*)(lds + B1L_OFF + tid * 4) = b1g[tid];
    if (tid < 16) *(float*)(lds + B2L_OFF + tid * 4) = b2g[tid];
    if (tid < 3)  *(float*)(lds + B3L_OFF + tid * 4) = b3g[tid];
    if (tid < 48) *(float*)(lds + W3L_OFF + tid * 4) = w3g[tid];

    __syncthreads();                 // init visible (full drain, once)
    COMMITQ(RA, 0);                  // q0 -> buf0
    __syncthreads();                 // buf0 ready

    f32x4 acc[4][2];

    // quarters: q0..q9 = (m,ks) pairs of whh0,wih1,whh1,wih2,whh2; q10 = w1
    #pragma unroll 1
    for (int t = 0; t < T; ++t) {
        const int bp = t & 1;
        // ----- layer 0: whh0 (A = plane0 old) -----
        COMMITQ(RB, bp ^ 1); LOADQ(1, 1, RA);       // commit q1, load q3
        ACC_INIT(0); XPART;
        GATEP(0, 0, bp);                            // q0
        BARX;
        COMMITQ(RC, bp); LOADQ(2, 0, RB);           // commit q2, load q4
        GATEP(0, 1, bp ^ 1);                        // q1
        BARX;
        CELLW(0, c0);                               // h0 -> plane0
        BARX;
        // ----- layer 1: wih1 (A=plane0 new), whh1 (A=plane1 old) -----
        COMMITQ(RA, bp ^ 1); LOADQ(2, 1, RC);       // commit q3, load q5
        ACC_INIT(1);
        GATEP(0, 0, bp);                            // q2
        BARX;
        COMMITQ(RB, bp); LOADQ(3, 0, RA);           // commit q4, load q6
        GATEP(0, 1, bp ^ 1);                        // q3
        BARX;
        COMMITQ(RC, bp ^ 1); LOADQ(3, 1, RB);       // commit q5, load q7
        GATEP(1, 0, bp);                            // q4
        BARX;
        COMMITQ(RA, bp); LOADQ(4, 0, RC);           // commit q6, load q8
        GATEP(1, 1, bp ^ 1);                        // q5
        BARX;
        CELLW(1, c1);                               // h1 -> plane1
        BARX;
        // ----- layer 2: wih2 (A=plane1 new), whh2 (A=plane2 old) -----
        COMMITQ(RB, bp ^ 1); LOADQ(4, 1, RA);       // commit q7, load q9
        ACC_INIT(2);
        GATEP(1, 0, bp);                            // q6
        BARX;
        COMMITQ(RC, bp); LOADW1(RB);                // commit q8, load q10 (w1)
        GATEP(1, 1, bp ^ 1);                        // q7
        BARX;
        COMMITQ(RA, bp ^ 1); LOADQ(0, 0, RC);       // commit q9, load q0'
        GATEP(2, 0, bp);                            // q8
        BARX;
        COMMITW1(RB, bp); LOADQ(0, 1, RA);          // commit q10 (w1), load q1'
        GATEP(2, 1, bp ^ 1);                        // q9
        BARX;
        CELLW(2, c2);                               // h2 -> plane2
        BARX;
        // ----- MLP head -----
        COMMITQ(RC, bp ^ 1); LOADQ(1, 0, RB);       // commit q0', load q2'
        MLP1(bp);                                   // y1 via MFMA (A=plane2, B=w1)
        BARX;
        MLP2;                                       // y1 -> y2 (VALU)
        BARX;
        MLP3_OUT;                                   // y2 -> XFB + out ring
        if ((t & 3) == 3) {                         // flush 4 buffered steps
            BARX;
            long tb = t - 3;
            #pragma unroll
            for (int it = 0; it < 2; ++it) {
                int i = it * NTHR + tid;
                if (i < 1536) {
                    int e = i / 12, j = i - e * 12;
                    out[(eg0 + e) * outs + tb * 3 + j] =
                        *(const float*)(lds + OUT_OFF + e * 48 + j * 4);
                }
            }
        }
        BARX;                                       // step boundary
        // ring rename: next step expects q1' in RB, q2' in RC
        { bf16x8 tmp = RB; RB = RA; RC = tmp; }
    }

    // tail flush (T not multiple of 4)
    int nst = T & 3;
    if (nst) {
        int nfl = BT * nst * 3;
        for (int i = tid; i < nfl; i += NTHR) {
            int e = i / (nst * 3), j = i - e * (nst * 3);
            out[(eg0 + e) * outs + (long)(T - nst) * 3 + j] =
                *(const float*)(lds + OUT_OFF + e * 48 + j * 4);
        }
    }
}

extern "C" void kernel_launch(void* const* d_in, const int* in_sizes, int n_in,
                              void* d_out, int out_size, void* d_ws, size_t ws_size,
                              hipStream_t stream)
{
    const float* noise = (const float*)d_in[0];
    const float* wih0  = (const float*)d_in[1];
    const float* whh0  = (const float*)d_in[2];
    const float* bih0  = (const float*)d_in[3];
    const float* bhh0  = (const float*)d_in[4];
    const float* wih1  = (const float*)d_in[5];
    const float* whh1  = (const float*)d_in[6];
    const float* bih1  = (const float*)d_in[7];
    const float* bhh1  = (const float*)d_in[8];
    const float* wih2  = (const float*)d_in[9];
    const float* whh2  = (const float*)d_in[10];
    const float* bih2  = (const float*)d_in[11];
    const float* bhh2  = (const float*)d_in[12];
    const float* w1g   = (const float*)d_in[13];
    const float* b1g   = (const float*)d_in[14];
    const float* w2g   = (const float*)d_in[15];
    const float* b2g   = (const float*)d_in[16];
    const float* w3g   = (const float*)d_in[17];
    const float* b3g   = (const float*)d_in[18];
    const int*   lenp  = (const int*)d_in[19];
    float* out = (float*)d_out;

    int B = in_sizes[0] / 3;              // 32768
    int grid = B / BT;                    // 256 blocks = 1 per CU

    prep_weights<<<41, 256, 0, stream>>>(whh0, wih1, whh1, wih2, whh2, w1g);

    hipFuncSetAttribute((const void*)lstm_mfma,
                        hipFuncAttributeMaxDynamicSharedMemorySize, LDS_TOTAL);
    lstm_mfma<<<grid, NTHR, LDS_TOTAL, stream>>>(
        noise, wih0, whh0, bih0, bhh0, wih1, whh1, bih1, bhh1,
        wih2, whh2, bih2, bhh2, w1g, b1g, w2g, b2g, w3g, b3g, lenp, out);
}